// Round 3
// baseline (249.424 us; speedup 1.0000x reference)
//
#include <hip/hip_runtime.h>
#include <hip/hip_bf16.h>

// tanh(X @ W^T + b): M=131072, N=K=256, fp32 in/out.
// R6: occupancy-first restructure. Block = 16-row chunk x 128 cols (col-half
// by bid parity), 4 waves x 32 cols (bW[8][2] = 64 regs). X staged fp32 via
// global_load_lds (no staging VGPRs) with XOR bank-swizzle through
// pre-swizzled source addresses. Direct scalar NT stores (no epilogue LDS).
// 768 blocks grid-stride over 16384 units, 3 blocks/CU, dbuf LDS 32 KB,
// chunk-ahead prefetch with counted vmcnt(8).

#define HIDDEN 256
#define M_TOTAL (16 * 8192)
#define UNITS 16384          // 8192 row-chunks x 2 col-halves
#define NBLK 768             // even: block's col-half = bid&1 is invariant

using bf16x8 = __attribute__((ext_vector_type(8))) __bf16;
using f32x4  = __attribute__((ext_vector_type(4))) float;

__device__ __forceinline__ void gload16(const void* g, void* l) {
    __builtin_amdgcn_global_load_lds(
        (const __attribute__((address_space(1))) void*)g,
        (__attribute__((address_space(3))) void*)l, 16, 0, 0);
}

// WF[((nb*8 + c)*4 + t)*512 + lane*8 + j] =
//   bf16( W[(nb*64 + t*16 + (lane&15))*256 + c*32 + (lane>>4)*8 + j] )
__global__ __launch_bounds__(256) void wfrag_kernel(const float* __restrict__ W,
                                                    __bf16* __restrict__ WF) {
    const int gid  = blockIdx.x * 256 + threadIdx.x;   // 0..8191
    const int lane = gid & 63;
    const int t    = (gid >> 6) & 3;
    const int c    = (gid >> 8) & 7;
    const int nb   = gid >> 11;
    const int lr = lane & 15, q = lane >> 4;
    const float* src = W + (size_t)(nb * 64 + t * 16 + lr) * HIDDEN + c * 32 + q * 8;
    float4 lo = *(const float4*)src;
    float4 hi = *(const float4*)(src + 4);
    bf16x8 v;
    v[0] = (__bf16)lo.x; v[1] = (__bf16)lo.y; v[2] = (__bf16)lo.z; v[3] = (__bf16)lo.w;
    v[4] = (__bf16)hi.x; v[5] = (__bf16)hi.y; v[6] = (__bf16)hi.z; v[7] = (__bf16)hi.w;
    *(bf16x8*)(WF + (size_t)gid * 8) = v;
}

__global__ __launch_bounds__(256, 3) void rotor_kernel(const float* __restrict__ X,
                                                       const __bf16* __restrict__ WF,
                                                       const float* __restrict__ bias,
                                                       float* __restrict__ Y) {
    // X double-buffer: 2 x 16 rows x 256 fp32 = 32 KB. Nothing else in LDS.
    __shared__ __align__(16) float sX[2][16 * 256];

    const int tid  = threadIdx.x;
    const int lane = tid & 63;
    const int wave = tid >> 6;
    const int lr = lane & 15, q = lane >> 4;
    const int bid = blockIdx.x;
    const int h   = bid & 1;          // col half, invariant per block

    // ---- this wave's 32-col W fragment set: 16 x bf16x8 = 64 regs ----
    const int nb  = h * 2 + (wave >> 1);
    const int tl0 = (wave & 1) * 2;
    const __bf16* wf = WF + (size_t)nb * (8 * 4 * 512) + lane * 8;
    bf16x8 bW[8][2];
#pragma unroll
    for (int c = 0; c < 8; ++c)
#pragma unroll
        for (int t = 0; t < 2; ++t)
            bW[c][t] = *(const bf16x8*)(wf + (c * 4 + tl0 + t) * 512);

    float bv[2];
#pragma unroll
    for (int t = 0; t < 2; ++t) bv[t] = bias[h * 128 + wave * 32 + t * 16 + lr];

    // ---- staging: wave stages rows wave*4..wave*4+3, 1 KB each.
    // LDS dest linear (base + lane*16); source byte offset pre-swizzled:
    // sw(r) = ((r&7)<<5) | ((r&8)<<1)  -> read-side 2-way conflicts only.
    int srcoff[4];
#pragma unroll
    for (int k = 0; k < 4; ++k) {
        const int r = wave * 4 + k;
        srcoff[k] = (lane * 16) ^ (((r & 7) << 5) | ((r & 8) << 1));
    }
    const int swr = ((lr & 7) << 3) | ((lr & 8) >> 1);   // word-granular read XOR

    // ---- prologue: stage unit bid into buf 0 ----
    {
        const int rc = bid >> 1;
#pragma unroll
        for (int k = 0; k < 4; ++k)
            gload16((const char*)X + (size_t)(rc * 16 + wave * 4 + k) * 1024 + srcoff[k],
                    (char*)&sX[0][(wave * 4 + k) * 256]);
    }
    asm volatile("s_waitcnt vmcnt(0)" ::: "memory");
    __builtin_amdgcn_s_barrier();
    asm volatile("" ::: "memory");

    int cur = 0;
#pragma unroll 1
    for (int u = bid; u < UNITS; u += NBLK) {
        const int rc = u >> 1;

        // prefetch next unit's X into the other buffer (DMA, no VGPRs)
        const int un = u + NBLK;
        if (un < UNITS) {
            const int rcn = un >> 1;
#pragma unroll
            for (int k = 0; k < 4; ++k)
                gload16((const char*)X + (size_t)(rcn * 16 + wave * 4 + k) * 1024 + srcoff[k],
                        (char*)&sX[cur ^ 1][(wave * 4 + k) * 256]);
        }

        // ---- compute: 16 rows x 32 cols per wave, K=256 ----
        const float* sxr = &sX[cur][lr * 256];
        f32x4 acc0 = {0.f, 0.f, 0.f, 0.f};
        f32x4 acc1 = {0.f, 0.f, 0.f, 0.f};
#pragma unroll
        for (int c = 0; c < 8; ++c) {
            const int b0 = c * 32 + q * 8;
            f32x4 lo = *(const f32x4*)(sxr + (b0 ^ swr));
            f32x4 hi = *(const f32x4*)(sxr + ((b0 + 4) ^ swr));
            bf16x8 a;
            a[0] = (__bf16)lo[0]; a[1] = (__bf16)lo[1];
            a[2] = (__bf16)lo[2]; a[3] = (__bf16)lo[3];
            a[4] = (__bf16)hi[0]; a[5] = (__bf16)hi[1];
            a[6] = (__bf16)hi[2]; a[7] = (__bf16)hi[3];
            acc0 = __builtin_amdgcn_mfma_f32_16x16x32_bf16(a, bW[c][0], acc0, 0, 0, 0);
            acc1 = __builtin_amdgcn_mfma_f32_16x16x32_bf16(a, bW[c][1], acc1, 0, 0, 0);
        }

        // ---- epilogue: bias + tanh, direct NT scalar stores (4x64B segs/instr) ----
        float* yb = Y + (size_t)(rc * 16 + q * 4) * HIDDEN + h * 128 + wave * 32 + lr;
#pragma unroll
        for (int t = 0; t < 2; ++t)
#pragma unroll
            for (int i = 0; i < 4; ++i) {
                float z = (t ? acc1[i] : acc0[i]) + bv[t];
                z = fminf(fmaxf(z, -10.f), 10.f);
                const float e2 = __expf(2.0f * z);
                __builtin_nontemporal_store(__fdividef(e2 - 1.0f, e2 + 1.0f),
                                            yb + (size_t)i * HIDDEN + t * 16);
            }

        // gloads (4) are older than the 8 NT stores -> vmcnt(8) waits loads only
        asm volatile("s_waitcnt vmcnt(8)" ::: "memory");
        __builtin_amdgcn_s_barrier();
        asm volatile("" ::: "memory");
        cur ^= 1;
    }
}

extern "C" void kernel_launch(void* const* d_in, const int* in_sizes, int n_in,
                              void* d_out, int out_size, void* d_ws, size_t ws_size,
                              hipStream_t stream) {
    const float* X    = (const float*)d_in[0];
    const float* W    = (const float*)d_in[1];
    const float* bias = (const float*)d_in[2];
    float* Y          = (float*)d_out;
    __bf16* WF        = (__bf16*)d_ws;     // 65536 bf16 = 128 KB

    wfrag_kernel<<<dim3(32), dim3(256), 0, stream>>>(W, WF);
    rotor_kernel<<<dim3(NBLK), dim3(256), 0, stream>>>(X, WF, bias, Y);
}